// Round 1
// baseline (819.796 us; speedup 1.0000x reference)
//
#include <hip/hip_runtime.h>
#include <math.h>

#define NN 100000
#define EE 1600000
#define DIN 128
#define C1 64   // HEADS*HID
#define C2 32   // D_OUT
#define NEG 0.2f

static __device__ __forceinline__ float leaky(float x) { return x > 0.f ? x : NEG * x; }

// ---------------- CSR build ----------------

__global__ void k_hist(const int* __restrict__ ei, int* __restrict__ deg) {
    int e = blockIdx.x * 256 + threadIdx.x;
    if (e < EE) atomicAdd(&deg[ei[EE + e]], 1);
}

// per-block exclusive scan of 1024 elements (256 thr x 4), store local scan + block sum
__global__ void k_scan1(const int* __restrict__ deg, int* __restrict__ rs, int* __restrict__ bsum) {
    __shared__ int s[256];
    int b = blockIdx.x, t = threadIdx.x;
    int base = b * 1024 + t * 4;
    int v[4];
    int run = 0;
#pragma unroll
    for (int j = 0; j < 4; j++) {
        int idx = base + j;
        int d = (idx < NN) ? deg[idx] : 0;
        v[j] = run;  // thread-local exclusive
        run += d;
    }
    int val = run;
    s[t] = val;
    __syncthreads();
    for (int off = 1; off < 256; off <<= 1) {
        int add = (t >= off) ? s[t - off] : 0;
        __syncthreads();
        val += add;
        s[t] = val;
        __syncthreads();
    }
    int texcl = val - run;  // exclusive across threads
#pragma unroll
    for (int j = 0; j < 4; j++) {
        int idx = base + j;
        if (idx < NN) rs[idx] = texcl + v[j];
    }
    if (t == 255) bsum[b] = val;
}

__global__ void k_scan2(const int* __restrict__ bsum, int* __restrict__ boff, int nb) {
    __shared__ int s[128];
    int t = threadIdx.x;
    int v = (t < nb) ? bsum[t] : 0;
    int val = v;
    s[t] = val;
    __syncthreads();
    for (int off = 1; off < 128; off <<= 1) {
        int add = (t >= off) ? s[t - off] : 0;
        __syncthreads();
        val += add;
        s[t] = val;
        __syncthreads();
    }
    if (t < nb) boff[t] = val - v;  // exclusive
}

__global__ void k_scan3(int* __restrict__ rs, const int* __restrict__ boff) {
    int base = blockIdx.x * 1024 + threadIdx.x * 4;
    int add = boff[blockIdx.x];
#pragma unroll
    for (int j = 0; j < 4; j++) {
        int idx = base + j;
        if (idx < NN) rs[idx] += add;
    }
}

__global__ void k_scatter(const int* __restrict__ ei, const int* __restrict__ rs,
                          int* __restrict__ cursor, int* __restrict__ csr) {
    int e = blockIdx.x * 256 + threadIdx.x;
    if (e < EE) {
        int s = ei[e];
        int d = ei[EE + e];
        int pos = atomicAdd(&cursor[d], 1);
        csr[rs[d] + pos] = s;
    }
}

// ---------------- GEMM1: h1 = x @ W1, fused al_src/al_dst ----------------
// block=256 (4 waves), 64-node tile. lane = out col (64), wave handles 16 nodes.
__global__ __launch_bounds__(256, 2) void k_gemm1(
    const float* __restrict__ x, const float* __restrict__ W1,
    const float* __restrict__ a_s, const float* __restrict__ a_d,
    float* __restrict__ h1, float* __restrict__ als, float* __restrict__ ald) {
    __shared__ float xs[64 * 128];   // 32 KB
    __shared__ float wsh[128 * 64];  // 32 KB
    int t = threadIdx.x;
    int base = blockIdx.x * 64;
    for (int i = t; i < 2048; i += 256) ((float4*)wsh)[i] = ((const float4*)W1)[i];
    int maxn = NN - base;
    if (maxn > 64) maxn = 64;
    for (int i = t; i < 2048; i += 256) {
        int flat = i * 4;
        int n = flat >> 7;
        if (n < maxn) *(float4*)&xs[flat] = *(const float4*)&x[(size_t)(base + n) * 128 + (flat & 127)];
    }
    __syncthreads();
    int w = t >> 6, c = t & 63;
    int nb = w * 16;
    float acc[16];
#pragma unroll
    for (int j = 0; j < 16; j++) acc[j] = 0.f;
    for (int k = 0; k < 128; k += 4) {
        float w0 = wsh[k * 64 + c], w1 = wsh[(k + 1) * 64 + c];
        float w2 = wsh[(k + 2) * 64 + c], w3 = wsh[(k + 3) * 64 + c];
#pragma unroll
        for (int j = 0; j < 16; j++) {
            float4 xv = *(float4*)&xs[(nb + j) * 128 + k];
            acc[j] = fmaf(xv.x, w0, acc[j]);
            acc[j] = fmaf(xv.y, w1, acc[j]);
            acc[j] = fmaf(xv.z, w2, acc[j]);
            acc[j] = fmaf(xv.w, w3, acc[j]);
        }
    }
    float s_a = a_s[c], d_a = a_d[c];  // a_src1 flat [4][16] == index c
    int hd = c >> 4;
#pragma unroll
    for (int j = 0; j < 16; j++) {
        int n = base + nb + j;
        float v = acc[j];
        float vs = v * s_a, vd = v * d_a;
#pragma unroll
        for (int off = 1; off < 16; off <<= 1) {  // reduce within 16-lane head group
            vs += __shfl_xor(vs, off, 64);
            vd += __shfl_xor(vd, off, 64);
        }
        if (n < NN) {
            h1[(size_t)n * 64 + c] = v;
            if ((c & 15) == 0) {
                als[n * 4 + hd] = vs;
                ald[n * 4 + hd] = vd;
            }
        }
    }
}

// ---------------- Edge pass 1: wave per dst node, lane = channel (64) ----------------
__global__ __launch_bounds__(256) void k_edge1(
    const int* __restrict__ csr, const int* __restrict__ rs, const int* __restrict__ deg,
    const float* __restrict__ h1, const float* __restrict__ als, const float* __restrict__ ald,
    const float* __restrict__ b1, float* __restrict__ x2) {
    int wid = (blockIdx.x * 256 + threadIdx.x) >> 6;
    if (wid >= NN) return;
    int c = threadIdx.x & 63, hd = c >> 4;
    int n = wid;
    float ad = ald[n * 4 + hd];
    // self-loop init (reference appends loops; order within segment is irrelevant)
    float l = leaky(als[n * 4 + hd] + ad);
    float m = l, z = 1.0f;
    float acc = h1[(size_t)n * 64 + c];
    int s0 = rs[n], d = deg[n];
    for (int i = 0; i < d; i++) {
        int src = csr[s0 + i];
        float ls = leaky(als[src * 4 + hd] + ad);
        float hv = h1[(size_t)src * 64 + c];
        float mn = fmaxf(m, ls);
        float sc = __expf(m - mn), p = __expf(ls - mn);
        z = z * sc + p;
        acc = acc * sc + p * hv;
        m = mn;
    }
    float o = acc / (z + 1e-16f) + b1[c];
    x2[(size_t)n * 64 + c] = o > 0.f ? o : expm1f(o);  // ELU
}

// ---------------- GEMM2: h2 = x2 @ W2, fused al2 ----------------
// block=256, 64-node tile; half-wave of 32 lanes = cols, 8 nodes each.
__global__ __launch_bounds__(256, 2) void k_gemm2(
    const float* __restrict__ x2, const float* __restrict__ W2,
    const float* __restrict__ a_s, const float* __restrict__ a_d,
    float* __restrict__ h2, float* __restrict__ als, float* __restrict__ ald) {
    __shared__ float xs[64 * 64];   // 16 KB
    __shared__ float wsh[64 * 32];  // 8 KB
    int t = threadIdx.x;
    int base = blockIdx.x * 64;
    for (int i = t; i < 512; i += 256) ((float4*)wsh)[i] = ((const float4*)W2)[i];
    int maxn = NN - base;
    if (maxn > 64) maxn = 64;
    for (int i = t; i < 1024; i += 256) {
        int flat = i * 4;
        int n = flat >> 6;
        if (n < maxn) *(float4*)&xs[flat] = *(const float4*)&x2[(size_t)(base + n) * 64 + (flat & 63)];
    }
    __syncthreads();
    int w = t >> 6, half = (t >> 5) & 1, c = t & 31;
    int nb = w * 16 + half * 8;
    float acc[8];
#pragma unroll
    for (int j = 0; j < 8; j++) acc[j] = 0.f;
    for (int k = 0; k < 64; k += 4) {
        float w0 = wsh[k * 32 + c], w1 = wsh[(k + 1) * 32 + c];
        float w2 = wsh[(k + 2) * 32 + c], w3 = wsh[(k + 3) * 32 + c];
#pragma unroll
        for (int j = 0; j < 8; j++) {
            float4 xv = *(float4*)&xs[(nb + j) * 64 + k];
            acc[j] = fmaf(xv.x, w0, acc[j]);
            acc[j] = fmaf(xv.y, w1, acc[j]);
            acc[j] = fmaf(xv.z, w2, acc[j]);
            acc[j] = fmaf(xv.w, w3, acc[j]);
        }
    }
    float s_a = a_s[c], d_a = a_d[c];
#pragma unroll
    for (int j = 0; j < 8; j++) {
        int n = base + nb + j;
        float v = acc[j];
        float vs = v * s_a, vd = v * d_a;
#pragma unroll
        for (int off = 1; off < 32; off <<= 1) {  // reduce within 32-lane half
            vs += __shfl_xor(vs, off, 64);
            vd += __shfl_xor(vd, off, 64);
        }
        if (n < NN) {
            h2[(size_t)n * 32 + c] = v;
            if (c == 0) {
                als[n] = vs;
                ald[n] = vd;
            }
        }
    }
}

// ---------------- Edge pass 2: 32-lane group per dst node ----------------
__global__ __launch_bounds__(256) void k_edge2(
    const int* __restrict__ csr, const int* __restrict__ rs, const int* __restrict__ deg,
    const float* __restrict__ h2, const float* __restrict__ als, const float* __restrict__ ald,
    const float* __restrict__ b2, float* __restrict__ out) {
    int gid = blockIdx.x * 256 + threadIdx.x;
    int n = gid >> 5;
    if (n >= NN) return;
    int c = gid & 31;
    float ad = ald[n];
    float l = leaky(als[n] + ad);
    float m = l, z = 1.0f;
    float acc = h2[(size_t)n * 32 + c];
    int s0 = rs[n], d = deg[n];
    for (int i = 0; i < d; i++) {
        int src = csr[s0 + i];
        float ls = leaky(als[src] + ad);
        float hv = h2[(size_t)src * 32 + c];
        float mn = fmaxf(m, ls);
        float sc = __expf(m - mn), p = __expf(ls - mn);
        z = z * sc + p;
        acc = acc * sc + p * hv;
        m = mn;
    }
    out[(size_t)n * 32 + c] = acc / (z + 1e-16f) + b2[c];  // mean over 1 head = identity
}

// ---------------- launcher ----------------
extern "C" void kernel_launch(void* const* d_in, const int* in_sizes, int n_in,
                              void* d_out, int out_size, void* d_ws, size_t ws_size,
                              hipStream_t stream) {
    const float* x = (const float*)d_in[0];
    const int* ei = (const int*)d_in[1];
    const float* W1 = (const float*)d_in[2];
    const float* as1 = (const float*)d_in[3];
    const float* ad1 = (const float*)d_in[4];
    const float* b1 = (const float*)d_in[5];
    const float* W2 = (const float*)d_in[6];
    const float* as2 = (const float*)d_in[7];
    const float* ad2 = (const float*)d_in[8];
    const float* b2 = (const float*)d_in[9];
    float* out = (float*)d_out;

    char* p = (char*)d_ws;
    auto alloc = [&](size_t bytes) -> char* {
        char* r = p;
        p += (bytes + 255) & ~(size_t)255;
        return r;
    };
    int* deg = (int*)alloc((size_t)NN * 4);
    int* cursor = (int*)alloc((size_t)NN * 4);
    int* rs = (int*)alloc((size_t)NN * 4);
    int* bsum = (int*)alloc(512);
    int* boff = (int*)alloc(512);
    int* csr = (int*)alloc((size_t)EE * 4);
    float* h1 = (float*)alloc((size_t)NN * C1 * 4);
    float* als1 = (float*)alloc((size_t)NN * 4 * 4);
    float* ald1 = (float*)alloc((size_t)NN * 4 * 4);
    float* x2 = (float*)alloc((size_t)NN * C1 * 4);
    float* h2 = (float*)alloc((size_t)NN * C2 * 4);
    float* als2 = (float*)alloc((size_t)NN * 4);
    float* ald2 = (float*)alloc((size_t)NN * 4);
    if ((size_t)(p - (char*)d_ws) > ws_size) return;  // ws too small: fail loudly via validation

    hipMemsetAsync(deg, 0, (size_t)NN * 4, stream);
    hipMemsetAsync(cursor, 0, (size_t)NN * 4, stream);

    int nb = (NN + 1023) / 1024;  // 98
    k_hist<<<(EE + 255) / 256, 256, 0, stream>>>(ei, deg);
    k_scan1<<<nb, 256, 0, stream>>>(deg, rs, bsum);
    k_scan2<<<1, 128, 0, stream>>>(bsum, boff, nb);
    k_scan3<<<nb, 256, 0, stream>>>(rs, boff);
    k_scatter<<<(EE + 255) / 256, 256, 0, stream>>>(ei, rs, cursor, csr);

    k_gemm1<<<(NN + 63) / 64, 256, 0, stream>>>(x, W1, as1, ad1, h1, als1, ald1);
    k_edge1<<<(NN * 64 + 255) / 256, 256, 0, stream>>>(csr, rs, deg, h1, als1, ald1, b1, x2);
    k_gemm2<<<(NN + 63) / 64, 256, 0, stream>>>(x2, W2, as2, ad2, h2, als2, ald2);
    k_edge2<<<(NN * 32 + 255) / 256, 256, 0, stream>>>(csr, rs, deg, h2, als2, ald2, b2, out);
}

// Round 2
// 498.728 us; speedup vs baseline: 1.6438x; 1.6438x over previous
//
#include <hip/hip_runtime.h>
#include <math.h>

#define NN 100000
#define EE 1600000
#define DIN 128
#define C1 64   // HEADS*HID
#define C2 32   // D_OUT
#define NEG 0.2f

static __device__ __forceinline__ float leaky(float x) { return x > 0.f ? x : NEG * x; }

// online-softmax merge of one (logit ls, value hv) into stream (m,z,a)
#define MERGE(m, z, a, ls, hv)                      \
    {                                               \
        float mn_ = fmaxf(m, ls);                   \
        float sc_ = __expf(m - mn_);                \
        float pp_ = __expf(ls - mn_);               \
        z = z * sc_ + pp_;                          \
        a = a * sc_ + pp_ * (hv);                   \
        m = mn_;                                    \
    }

// ---------------- CSR build ----------------

__global__ void k_hist(const int* __restrict__ ei, int* __restrict__ deg) {
    int e = blockIdx.x * 256 + threadIdx.x;
    if (e < EE) atomicAdd(&deg[ei[EE + e]], 1);
}

__global__ void k_scan1(const int* __restrict__ deg, int* __restrict__ rs, int* __restrict__ bsum) {
    __shared__ int s[256];
    int b = blockIdx.x, t = threadIdx.x;
    int base = b * 1024 + t * 4;
    int v[4];
    int run = 0;
#pragma unroll
    for (int j = 0; j < 4; j++) {
        int idx = base + j;
        int d = (idx < NN) ? deg[idx] : 0;
        v[j] = run;
        run += d;
    }
    int val = run;
    s[t] = val;
    __syncthreads();
    for (int off = 1; off < 256; off <<= 1) {
        int add = (t >= off) ? s[t - off] : 0;
        __syncthreads();
        val += add;
        s[t] = val;
        __syncthreads();
    }
    int texcl = val - run;
#pragma unroll
    for (int j = 0; j < 4; j++) {
        int idx = base + j;
        if (idx < NN) rs[idx] = texcl + v[j];
    }
    if (t == 255) bsum[b] = val;
}

__global__ void k_scan2(const int* __restrict__ bsum, int* __restrict__ boff, int nb) {
    __shared__ int s[128];
    int t = threadIdx.x;
    int v = (t < nb) ? bsum[t] : 0;
    int val = v;
    s[t] = val;
    __syncthreads();
    for (int off = 1; off < 128; off <<= 1) {
        int add = (t >= off) ? s[t - off] : 0;
        __syncthreads();
        val += add;
        s[t] = val;
        __syncthreads();
    }
    if (t < nb) boff[t] = val - v;
}

__global__ void k_scan3(int* __restrict__ rs, const int* __restrict__ boff) {
    int base = blockIdx.x * 1024 + threadIdx.x * 4;
    int add = boff[blockIdx.x];
#pragma unroll
    for (int j = 0; j < 4; j++) {
        int idx = base + j;
        if (idx < NN) rs[idx] += add;
    }
}

__global__ void k_scatter(const int* __restrict__ ei, const int* __restrict__ rs,
                          int* __restrict__ cursor, int* __restrict__ csr) {
    int e = blockIdx.x * 256 + threadIdx.x;
    if (e < EE) {
        int s = ei[e];
        int d = ei[EE + e];
        int pos = atomicAdd(&cursor[d], 1);
        csr[rs[d] + pos] = s;
    }
}

// ---------------- GEMM1: h1 = x @ W1, fused al_src/al_dst ----------------
__global__ __launch_bounds__(256, 2) void k_gemm1(
    const float* __restrict__ x, const float* __restrict__ W1,
    const float* __restrict__ a_s, const float* __restrict__ a_d,
    float* __restrict__ h1, float* __restrict__ als, float* __restrict__ ald) {
    __shared__ float xs[64 * 128];   // 32 KB
    __shared__ float wsh[128 * 64];  // 32 KB
    int t = threadIdx.x;
    int base = blockIdx.x * 64;
    for (int i = t; i < 2048; i += 256) ((float4*)wsh)[i] = ((const float4*)W1)[i];
    int maxn = NN - base;
    if (maxn > 64) maxn = 64;
    for (int i = t; i < 2048; i += 256) {
        int flat = i * 4;
        int n = flat >> 7;
        if (n < maxn) *(float4*)&xs[flat] = *(const float4*)&x[(size_t)(base + n) * 128 + (flat & 127)];
    }
    __syncthreads();
    int w = t >> 6, c = t & 63;
    int nb = w * 16;
    float acc[16];
#pragma unroll
    for (int j = 0; j < 16; j++) acc[j] = 0.f;
    for (int k = 0; k < 128; k += 4) {
        float w0 = wsh[k * 64 + c], w1 = wsh[(k + 1) * 64 + c];
        float w2 = wsh[(k + 2) * 64 + c], w3 = wsh[(k + 3) * 64 + c];
#pragma unroll
        for (int j = 0; j < 16; j++) {
            float4 xv = *(float4*)&xs[(nb + j) * 128 + k];
            acc[j] = fmaf(xv.x, w0, acc[j]);
            acc[j] = fmaf(xv.y, w1, acc[j]);
            acc[j] = fmaf(xv.z, w2, acc[j]);
            acc[j] = fmaf(xv.w, w3, acc[j]);
        }
    }
    float s_a = a_s[c], d_a = a_d[c];
    int hd = c >> 4;
#pragma unroll
    for (int j = 0; j < 16; j++) {
        int n = base + nb + j;
        float v = acc[j];
        float vs = v * s_a, vd = v * d_a;
#pragma unroll
        for (int off = 1; off < 16; off <<= 1) {
            vs += __shfl_xor(vs, off, 64);
            vd += __shfl_xor(vd, off, 64);
        }
        if (n < NN) {
            h1[(size_t)n * 64 + c] = v;
            if ((c & 15) == 0) {
                als[n * 4 + hd] = vs;
                ald[n * 4 + hd] = vd;
            }
        }
    }
}

// ---------------- Edge pass 1 + fused GEMM2 ----------------
// wave per dst node (4 nodes/block), lane = channel (64). 4-stream online softmax.
// Epilogue: x2 row lives in registers -> LDS row buffer -> h2 = x2 @ W2 in-block.
__global__ __launch_bounds__(256) void k_edge1(
    const int* __restrict__ csr, const int* __restrict__ rs, const int* __restrict__ deg,
    const float* __restrict__ h1, const float* __restrict__ als, const float* __restrict__ ald,
    const float* __restrict__ b1, const float* __restrict__ W2,
    const float* __restrict__ as2, const float* __restrict__ ad2,
    float* __restrict__ h2, float* __restrict__ als2, float* __restrict__ ald2) {
    __shared__ float wsh[64 * 32];  // 8 KB: W2
    __shared__ float xld[4][64];    // per-wave x2 row
    int t = threadIdx.x;
    for (int i = t; i < 512; i += 256) ((float4*)wsh)[i] = ((const float4*)W2)[i];
    int w = t >> 6, c = t & 63, hd = c >> 4;
    int n = blockIdx.x * 4 + w;  // NN % 4 == 0 -> always valid, no early exit
    float ad = ald[n * 4 + hd];
    // stream 0 seeded with the self-loop
    float m0 = leaky(als[n * 4 + hd] + ad), z0 = 1.f, a0 = h1[(size_t)n * 64 + c];
    float m1 = -INFINITY, z1 = 0.f, a1 = 0.f;
    float m2 = -INFINITY, z2 = 0.f, a2 = 0.f;
    float m3 = -INFINITY, z3 = 0.f, a3 = 0.f;
    int s0 = rs[n], d = deg[n];
    int i = 0;
    for (; i + 4 <= d; i += 4) {
        int sA = csr[s0 + i], sB = csr[s0 + i + 1], sC = csr[s0 + i + 2], sD = csr[s0 + i + 3];
        float lA = leaky(als[sA * 4 + hd] + ad);
        float lB = leaky(als[sB * 4 + hd] + ad);
        float lC = leaky(als[sC * 4 + hd] + ad);
        float lD = leaky(als[sD * 4 + hd] + ad);
        float hA = h1[(size_t)sA * 64 + c];
        float hB = h1[(size_t)sB * 64 + c];
        float hC = h1[(size_t)sC * 64 + c];
        float hD = h1[(size_t)sD * 64 + c];
        MERGE(m0, z0, a0, lA, hA);
        MERGE(m1, z1, a1, lB, hB);
        MERGE(m2, z2, a2, lC, hC);
        MERGE(m3, z3, a3, lD, hD);
    }
    for (; i < d; i++) {
        int s = csr[s0 + i];
        float ls = leaky(als[s * 4 + hd] + ad);
        float hv = h1[(size_t)s * 64 + c];
        MERGE(m0, z0, a0, ls, hv);
    }
    // merge 4 streams (m0 always finite; empty streams contribute 0)
    float mm = fmaxf(fmaxf(m0, m1), fmaxf(m2, m3));
    float e0 = __expf(m0 - mm), e1 = __expf(m1 - mm), e2 = __expf(m2 - mm), e3 = __expf(m3 - mm);
    float z = z0 * e0 + z1 * e1 + z2 * e2 + z3 * e3;
    float acc = a0 * e0 + a1 * e1 + a2 * e2 + a3 * e3;
    float o = acc / (z + 1e-16f) + b1[c];
    float xv = o > 0.f ? o : expm1f(o);  // ELU -> x2 value for (n, c)

    // ---- fused GEMM2: h2[n] = x2row @ W2 ----
    xld[w][c] = xv;
    __syncthreads();  // covers wsh writes too; all 256 threads reach here
    int hi = c >> 5, cc = c & 31;
    float accn = 0.f;
#pragma unroll
    for (int k = 0; k < 32; k++) {
        float xk = xld[w][hi * 32 + k];              // broadcast per half-wave
        accn = fmaf(xk, wsh[(hi * 32 + k) * 32 + cc], accn);
    }
    accn += __shfl_xor(accn, 32, 64);  // combine k-halves; lanes 0-31 hold h2[n][cc]
    float vs = accn * as2[cc], vd = accn * ad2[cc];
#pragma unroll
    for (int off = 1; off < 32; off <<= 1) {
        vs += __shfl_xor(vs, off, 64);
        vd += __shfl_xor(vd, off, 64);
    }
    if (c < 32) h2[(size_t)n * 32 + c] = accn;
    if (c == 0) {
        als2[n] = vs;
        ald2[n] = vd;
    }
}

// ---------------- Edge pass 2: 32-lane group per dst node, 4-stream ----------------
__global__ __launch_bounds__(256) void k_edge2(
    const int* __restrict__ csr, const int* __restrict__ rs, const int* __restrict__ deg,
    const float* __restrict__ h2, const float* __restrict__ als, const float* __restrict__ ald,
    const float* __restrict__ b2, float* __restrict__ out) {
    int gid = blockIdx.x * 256 + threadIdx.x;
    int n = gid >> 5;
    if (n >= NN) return;
    int c = gid & 31;
    float ad = ald[n];
    float m0 = leaky(als[n] + ad), z0 = 1.f, a0 = h2[(size_t)n * 32 + c];
    float m1 = -INFINITY, z1 = 0.f, a1 = 0.f;
    float m2 = -INFINITY, z2 = 0.f, a2 = 0.f;
    float m3 = -INFINITY, z3 = 0.f, a3 = 0.f;
    int s0 = rs[n], d = deg[n];
    int i = 0;
    for (; i + 4 <= d; i += 4) {
        int sA = csr[s0 + i], sB = csr[s0 + i + 1], sC = csr[s0 + i + 2], sD = csr[s0 + i + 3];
        float lA = leaky(als[sA] + ad);
        float lB = leaky(als[sB] + ad);
        float lC = leaky(als[sC] + ad);
        float lD = leaky(als[sD] + ad);
        float hA = h2[(size_t)sA * 32 + c];
        float hB = h2[(size_t)sB * 32 + c];
        float hC = h2[(size_t)sC * 32 + c];
        float hD = h2[(size_t)sD * 32 + c];
        MERGE(m0, z0, a0, lA, hA);
        MERGE(m1, z1, a1, lB, hB);
        MERGE(m2, z2, a2, lC, hC);
        MERGE(m3, z3, a3, lD, hD);
    }
    for (; i < d; i++) {
        int s = csr[s0 + i];
        float ls = leaky(als[s] + ad);
        float hv = h2[(size_t)s * 32 + c];
        MERGE(m0, z0, a0, ls, hv);
    }
    float mm = fmaxf(fmaxf(m0, m1), fmaxf(m2, m3));
    float e0 = __expf(m0 - mm), e1 = __expf(m1 - mm), e2 = __expf(m2 - mm), e3 = __expf(m3 - mm);
    float z = z0 * e0 + z1 * e1 + z2 * e2 + z3 * e3;
    float acc = a0 * e0 + a1 * e1 + a2 * e2 + a3 * e3;
    out[(size_t)n * 32 + c] = acc / (z + 1e-16f) + b2[c];
}

// ---------------- launcher ----------------
extern "C" void kernel_launch(void* const* d_in, const int* in_sizes, int n_in,
                              void* d_out, int out_size, void* d_ws, size_t ws_size,
                              hipStream_t stream) {
    const float* x = (const float*)d_in[0];
    const int* ei = (const int*)d_in[1];
    const float* W1 = (const float*)d_in[2];
    const float* as1 = (const float*)d_in[3];
    const float* ad1 = (const float*)d_in[4];
    const float* b1 = (const float*)d_in[5];
    const float* W2 = (const float*)d_in[6];
    const float* as2 = (const float*)d_in[7];
    const float* ad2 = (const float*)d_in[8];
    const float* b2 = (const float*)d_in[9];
    float* out = (float*)d_out;

    char* p = (char*)d_ws;
    auto alloc = [&](size_t bytes) -> char* {
        char* r = p;
        p += (bytes + 255) & ~(size_t)255;
        return r;
    };
    int* deg = (int*)alloc((size_t)NN * 4);
    int* cursor = (int*)alloc((size_t)NN * 4);
    int* rs = (int*)alloc((size_t)NN * 4);
    int* bsum = (int*)alloc(512);
    int* boff = (int*)alloc(512);
    int* csr = (int*)alloc((size_t)EE * 4);
    float* h1 = (float*)alloc((size_t)NN * C1 * 4);
    float* als1 = (float*)alloc((size_t)NN * 4 * 4);
    float* ald1 = (float*)alloc((size_t)NN * 4 * 4);
    float* h2 = (float*)alloc((size_t)NN * C2 * 4);
    float* als2 = (float*)alloc((size_t)NN * 4);
    float* ald2 = (float*)alloc((size_t)NN * 4);
    (void)ws_size;

    hipMemsetAsync(deg, 0, (size_t)NN * 4, stream);
    hipMemsetAsync(cursor, 0, (size_t)NN * 4, stream);

    int nb = (NN + 1023) / 1024;  // 98
    k_hist<<<(EE + 255) / 256, 256, 0, stream>>>(ei, deg);
    k_scan1<<<nb, 256, 0, stream>>>(deg, rs, bsum);
    k_scan2<<<1, 128, 0, stream>>>(bsum, boff, nb);
    k_scan3<<<nb, 256, 0, stream>>>(rs, boff);
    k_scatter<<<(EE + 255) / 256, 256, 0, stream>>>(ei, rs, cursor, csr);

    k_gemm1<<<(NN + 63) / 64, 256, 0, stream>>>(x, W1, as1, ad1, h1, als1, ald1);
    k_edge1<<<NN / 4, 256, 0, stream>>>(csr, rs, deg, h1, als1, ald1, b1, W2, as2, ad2,
                                        h2, als2, ald2);
    k_edge2<<<(NN * 32 + 255) / 256, 256, 0, stream>>>(csr, rs, deg, h2, als2, ald2, b2, out);
}

// Round 3
// 366.418 us; speedup vs baseline: 2.2373x; 1.3611x over previous
//
#include <hip/hip_runtime.h>
#include <math.h>

#define NN 100000
#define EE 1600000
#define DIN 128
#define C1 64   // HEADS*HID
#define C2 32   // D_OUT
#define NEG 0.2f

#define NB 1024   // coarse buckets
#define BSH 7     // bucket = dst >> 7 (128 nodes per bucket)
#define EPB 4096  // edges per binning block

static __device__ __forceinline__ float leaky(float x) { return x > 0.f ? x : NEG * x; }

#define MERGE(m, z, a, ls, hv)                      \
    {                                               \
        float mn_ = fmaxf(m, ls);                   \
        float sc_ = __expf(m - mn_);                \
        float pp_ = __expf(ls - mn_);               \
        z = z * sc_ + pp_;                          \
        a = a * sc_ + pp_ * (hv);                   \
        m = mn_;                                    \
    }

// ---------------- CSR build: bucket-binned counting sort ----------------

__global__ __launch_bounds__(256) void k_chist(const int* __restrict__ ei, int* __restrict__ bhist) {
    __shared__ int h[NB];
    int t = threadIdx.x;
    for (int i = t; i < NB; i += 256) h[i] = 0;
    __syncthreads();
    int e0 = blockIdx.x * EPB;
#pragma unroll
    for (int j = 0; j < 16; j++) {
        int e = e0 + t + 256 * j;
        if (e < EE) atomicAdd(&h[ei[EE + e] >> BSH], 1);
    }
    __syncthreads();
    for (int i = t; i < NB; i += 256) {
        int c = h[i];
        if (c) atomicAdd(&bhist[i], c);
    }
}

__global__ __launch_bounds__(256) void k_bscan(const int* __restrict__ bhist,
                                               int* __restrict__ gbase, int* __restrict__ gcur) {
    __shared__ int s[256];
    int t = threadIdx.x;
    int base = t * 4;
    int v[4];
    int run = 0;
#pragma unroll
    for (int j = 0; j < 4; j++) {
        v[j] = run;
        run += bhist[base + j];
    }
    int val = run;
    s[t] = val;
    __syncthreads();
    for (int off = 1; off < 256; off <<= 1) {
        int add = (t >= off) ? s[t - off] : 0;
        __syncthreads();
        val += add;
        s[t] = val;
        __syncthreads();
    }
    int texcl = val - run;
#pragma unroll
    for (int j = 0; j < 4; j++) {
        gbase[base + j] = texcl + v[j];
        gcur[base + j] = texcl + v[j];
    }
}

__global__ __launch_bounds__(256) void k_bin(const int* __restrict__ ei, int* __restrict__ gcur,
                                             int2* __restrict__ binned) {
    __shared__ int h[NB];
    __shared__ int base[NB];
    int t = threadIdx.x;
    for (int i = t; i < NB; i += 256) h[i] = 0;
    __syncthreads();
    int e0 = blockIdx.x * EPB;
    int src[16], dst[16];
#pragma unroll
    for (int j = 0; j < 16; j++) {
        int e = e0 + t + 256 * j;
        if (e < EE) {
            src[j] = ei[e];
            dst[j] = ei[EE + e];
            atomicAdd(&h[dst[j] >> BSH], 1);
        } else
            dst[j] = -1;
    }
    __syncthreads();
    for (int i = t; i < NB; i += 256) {
        int c = h[i];
        if (c) base[i] = atomicAdd(&gcur[i], c);
        h[i] = 0;  // reuse as local cursor
    }
    __syncthreads();
#pragma unroll
    for (int j = 0; j < 16; j++) {
        if (dst[j] >= 0) {
            int b = dst[j] >> BSH;
            int r = atomicAdd(&h[b], 1);
            binned[base[b] + r] = make_int2(src[j], dst[j]);
        }
    }
}

// one block per bucket: counting sort of its edges; writes deg, rs, csr
__global__ __launch_bounds__(256) void k_bsort(const int2* __restrict__ binned,
                                               const int* __restrict__ gbase,
                                               const int* __restrict__ bhist,
                                               int* __restrict__ rs, int* __restrict__ deg,
                                               int* __restrict__ csr) {
    __shared__ int h[128], cur[128], sc[128];
    int b = blockIdx.x, t = threadIdx.x;
    if (t < 128) h[t] = 0;
    __syncthreads();
    int gb = gbase[b], cnt = bhist[b];
    for (int i = t; i < cnt; i += 256) atomicAdd(&h[binned[gb + i].y & 127], 1);
    __syncthreads();
    if (t < 128) sc[t] = h[t];
    __syncthreads();
    for (int off = 1; off < 128; off <<= 1) {
        int add = 0;
        if (t < 128 && t >= off) add = sc[t - off];
        __syncthreads();
        if (t < 128) sc[t] += add;
        __syncthreads();
    }
    if (t < 128) {
        int node = b * 128 + t;
        int excl = sc[t] - h[t];
        if (node < NN) {
            rs[node] = gb + excl;
            deg[node] = h[t];
        }
        cur[t] = excl;
    }
    __syncthreads();
    for (int i = t; i < cnt; i += 256) {
        int2 e = binned[gb + i];
        int r = atomicAdd(&cur[e.y & 127], 1);
        csr[gb + r] = e.x;
    }
}

// ---------------- GEMM1: h1 = x @ W1, fused al_src/al_dst ----------------
__global__ __launch_bounds__(256, 2) void k_gemm1(
    const float* __restrict__ x, const float* __restrict__ W1,
    const float* __restrict__ a_s, const float* __restrict__ a_d,
    float* __restrict__ h1, float* __restrict__ als, float* __restrict__ ald) {
    __shared__ float xs[64 * 128];   // 32 KB
    __shared__ float wsh[128 * 64];  // 32 KB
    int t = threadIdx.x;
    int base = blockIdx.x * 64;
    for (int i = t; i < 2048; i += 256) ((float4*)wsh)[i] = ((const float4*)W1)[i];
    int maxn = NN - base;
    if (maxn > 64) maxn = 64;
    for (int i = t; i < 2048; i += 256) {
        int flat = i * 4;
        int n = flat >> 7;
        if (n < maxn) *(float4*)&xs[flat] = *(const float4*)&x[(size_t)(base + n) * 128 + (flat & 127)];
    }
    __syncthreads();
    int w = t >> 6, c = t & 63;
    int nb = w * 16;
    float acc[16];
#pragma unroll
    for (int j = 0; j < 16; j++) acc[j] = 0.f;
    for (int k = 0; k < 128; k += 4) {
        float w0 = wsh[k * 64 + c], w1 = wsh[(k + 1) * 64 + c];
        float w2 = wsh[(k + 2) * 64 + c], w3 = wsh[(k + 3) * 64 + c];
#pragma unroll
        for (int j = 0; j < 16; j++) {
            float4 xv = *(float4*)&xs[(nb + j) * 128 + k];
            acc[j] = fmaf(xv.x, w0, acc[j]);
            acc[j] = fmaf(xv.y, w1, acc[j]);
            acc[j] = fmaf(xv.z, w2, acc[j]);
            acc[j] = fmaf(xv.w, w3, acc[j]);
        }
    }
    float s_a = a_s[c], d_a = a_d[c];
    int hd = c >> 4;
#pragma unroll
    for (int j = 0; j < 16; j++) {
        int n = base + nb + j;
        float v = acc[j];
        float vs = v * s_a, vd = v * d_a;
#pragma unroll
        for (int off = 1; off < 16; off <<= 1) {
            vs += __shfl_xor(vs, off, 64);
            vd += __shfl_xor(vd, off, 64);
        }
        if (n < NN) {
            h1[(size_t)n * 64 + c] = v;
            if ((c & 15) == 0) {
                als[n * 4 + hd] = vs;
                ald[n * 4 + hd] = vd;
            }
        }
    }
}

// ---------------- Edge pass 1 + fused GEMM2 ----------------
__global__ __launch_bounds__(256) void k_edge1(
    const int* __restrict__ csr, const int* __restrict__ rs, const int* __restrict__ deg,
    const float* __restrict__ h1, const float* __restrict__ als, const float* __restrict__ ald,
    const float* __restrict__ b1, const float* __restrict__ W2,
    const float* __restrict__ as2, const float* __restrict__ ad2,
    float* __restrict__ h2, float* __restrict__ als2, float* __restrict__ ald2) {
    __shared__ float wsh[64 * 32];  // 8 KB: W2
    __shared__ float xld[4][64];    // per-wave x2 row
    int t = threadIdx.x;
    for (int i = t; i < 512; i += 256) ((float4*)wsh)[i] = ((const float4*)W2)[i];
    int w = t >> 6, c = t & 63, hd = c >> 4;
    int n = blockIdx.x * 4 + w;  // NN % 4 == 0
    float ad = ald[n * 4 + hd];
    float m0 = leaky(als[n * 4 + hd] + ad), z0 = 1.f, a0 = h1[(size_t)n * 64 + c];
    float m1 = -INFINITY, z1 = 0.f, a1 = 0.f;
    float m2 = -INFINITY, z2 = 0.f, a2 = 0.f;
    float m3 = -INFINITY, z3 = 0.f, a3 = 0.f;
    int s0 = rs[n], d = deg[n];
    int i = 0;
    for (; i + 4 <= d; i += 4) {
        int sA = csr[s0 + i], sB = csr[s0 + i + 1], sC = csr[s0 + i + 2], sD = csr[s0 + i + 3];
        float lA = leaky(als[sA * 4 + hd] + ad);
        float lB = leaky(als[sB * 4 + hd] + ad);
        float lC = leaky(als[sC * 4 + hd] + ad);
        float lD = leaky(als[sD * 4 + hd] + ad);
        float hA = h1[(size_t)sA * 64 + c];
        float hB = h1[(size_t)sB * 64 + c];
        float hC = h1[(size_t)sC * 64 + c];
        float hD = h1[(size_t)sD * 64 + c];
        MERGE(m0, z0, a0, lA, hA);
        MERGE(m1, z1, a1, lB, hB);
        MERGE(m2, z2, a2, lC, hC);
        MERGE(m3, z3, a3, lD, hD);
    }
    for (; i < d; i++) {
        int s = csr[s0 + i];
        float ls = leaky(als[s * 4 + hd] + ad);
        float hv = h1[(size_t)s * 64 + c];
        MERGE(m0, z0, a0, ls, hv);
    }
    float mm = fmaxf(fmaxf(m0, m1), fmaxf(m2, m3));
    float e0 = __expf(m0 - mm), e1 = __expf(m1 - mm), e2 = __expf(m2 - mm), e3 = __expf(m3 - mm);
    float z = z0 * e0 + z1 * e1 + z2 * e2 + z3 * e3;
    float acc = a0 * e0 + a1 * e1 + a2 * e2 + a3 * e3;
    float o = acc / (z + 1e-16f) + b1[c];
    float xv = o > 0.f ? o : expm1f(o);  // ELU

    // ---- fused GEMM2 ----
    xld[w][c] = xv;
    __syncthreads();
    int hi = c >> 5, cc = c & 31;
    float accn = 0.f;
#pragma unroll
    for (int k = 0; k < 32; k++) {
        float xk = xld[w][hi * 32 + k];
        accn = fmaf(xk, wsh[(hi * 32 + k) * 32 + cc], accn);
    }
    accn += __shfl_xor(accn, 32, 64);
    float vs = accn * as2[cc], vd = accn * ad2[cc];
#pragma unroll
    for (int off = 1; off < 32; off <<= 1) {
        vs += __shfl_xor(vs, off, 64);
        vd += __shfl_xor(vd, off, 64);
    }
    if (c < 32) h2[(size_t)n * 32 + c] = accn;
    if (c == 0) {
        als2[n] = vs;
        ald2[n] = vd;
    }
}

// ---------------- Edge pass 2 ----------------
__global__ __launch_bounds__(256) void k_edge2(
    const int* __restrict__ csr, const int* __restrict__ rs, const int* __restrict__ deg,
    const float* __restrict__ h2, const float* __restrict__ als, const float* __restrict__ ald,
    const float* __restrict__ b2, float* __restrict__ out) {
    int gid = blockIdx.x * 256 + threadIdx.x;
    int n = gid >> 5;
    if (n >= NN) return;
    int c = gid & 31;
    float ad = ald[n];
    float m0 = leaky(als[n] + ad), z0 = 1.f, a0 = h2[(size_t)n * 32 + c];
    float m1 = -INFINITY, z1 = 0.f, a1 = 0.f;
    float m2 = -INFINITY, z2 = 0.f, a2 = 0.f;
    float m3 = -INFINITY, z3 = 0.f, a3 = 0.f;
    int s0 = rs[n], d = deg[n];
    int i = 0;
    for (; i + 4 <= d; i += 4) {
        int sA = csr[s0 + i], sB = csr[s0 + i + 1], sC = csr[s0 + i + 2], sD = csr[s0 + i + 3];
        float lA = leaky(als[sA] + ad);
        float lB = leaky(als[sB] + ad);
        float lC = leaky(als[sC] + ad);
        float lD = leaky(als[sD] + ad);
        float hA = h2[(size_t)sA * 32 + c];
        float hB = h2[(size_t)sB * 32 + c];
        float hC = h2[(size_t)sC * 32 + c];
        float hD = h2[(size_t)sD * 32 + c];
        MERGE(m0, z0, a0, lA, hA);
        MERGE(m1, z1, a1, lB, hB);
        MERGE(m2, z2, a2, lC, hC);
        MERGE(m3, z3, a3, lD, hD);
    }
    for (; i < d; i++) {
        int s = csr[s0 + i];
        float ls = leaky(als[s] + ad);
        float hv = h2[(size_t)s * 32 + c];
        MERGE(m0, z0, a0, ls, hv);
    }
    float mm = fmaxf(fmaxf(m0, m1), fmaxf(m2, m3));
    float e0 = __expf(m0 - mm), e1 = __expf(m1 - mm), e2 = __expf(m2 - mm), e3 = __expf(m3 - mm);
    float z = z0 * e0 + z1 * e1 + z2 * e2 + z3 * e3;
    float acc = a0 * e0 + a1 * e1 + a2 * e2 + a3 * e3;
    out[(size_t)n * 32 + c] = acc / (z + 1e-16f) + b2[c];
}

// ---------------- launcher ----------------
extern "C" void kernel_launch(void* const* d_in, const int* in_sizes, int n_in,
                              void* d_out, int out_size, void* d_ws, size_t ws_size,
                              hipStream_t stream) {
    const float* x = (const float*)d_in[0];
    const int* ei = (const int*)d_in[1];
    const float* W1 = (const float*)d_in[2];
    const float* as1 = (const float*)d_in[3];
    const float* ad1 = (const float*)d_in[4];
    const float* b1 = (const float*)d_in[5];
    const float* W2 = (const float*)d_in[6];
    const float* as2 = (const float*)d_in[7];
    const float* ad2 = (const float*)d_in[8];
    const float* b2 = (const float*)d_in[9];
    float* out = (float*)d_out;

    char* p = (char*)d_ws;
    auto alloc = [&](size_t bytes) -> char* {
        char* r = p;
        p += (bytes + 255) & ~(size_t)255;
        return r;
    };
    int* csr = (int*)alloc((size_t)EE * 4);
    int* rs = (int*)alloc((size_t)NN * 4);
    int* deg = (int*)alloc((size_t)NN * 4);
    int* bhist = (int*)alloc(NB * 4);
    int* gbase = (int*)alloc(NB * 4);
    int* gcur = (int*)alloc(NB * 4);
    float* h1 = (float*)alloc((size_t)NN * C1 * 4);
    float* als1 = (float*)alloc((size_t)NN * 4 * 4);
    float* ald1 = (float*)alloc((size_t)NN * 4 * 4);
    // region X: binned (12.8 MB) aliases h2/als2/ald2 (13.6 MB); binned is dead
    // before k_edge1 writes h2.
    char* regionX = alloc((size_t)NN * C2 * 4 + (size_t)NN * 4 * 2 + 512);
    int2* binned = (int2*)regionX;
    float* h2 = (float*)regionX;
    float* als2 = (float*)(regionX + (size_t)NN * C2 * 4);
    float* ald2 = (float*)(regionX + (size_t)NN * C2 * 4 + (size_t)NN * 4);
    (void)ws_size;

    hipMemsetAsync(bhist, 0, NB * 4, stream);

    int nbin = (EE + EPB - 1) / EPB;  // 391
    k_chist<<<nbin, 256, 0, stream>>>(ei, bhist);
    k_bscan<<<1, 256, 0, stream>>>(bhist, gbase, gcur);
    k_bin<<<nbin, 256, 0, stream>>>(ei, gcur, binned);
    k_bsort<<<(NN + 127) / 128, 256, 0, stream>>>(binned, gbase, bhist, rs, deg, csr);

    k_gemm1<<<(NN + 63) / 64, 256, 0, stream>>>(x, W1, as1, ad1, h1, als1, ald1);
    k_edge1<<<NN / 4, 256, 0, stream>>>(csr, rs, deg, h1, als1, ald1, b1, W2, as2, ad2,
                                        h2, als2, ald2);
    k_edge2<<<(NN * 32 + 255) / 256, 256, 0, stream>>>(csr, rs, deg, h2, als2, ald2, b2, out);
}

// Round 4
// 354.068 us; speedup vs baseline: 2.3154x; 1.0349x over previous
//
#include <hip/hip_runtime.h>
#include <math.h>

#define NN 100000
#define EE 1600000
#define DIN 128
#define C1 64   // HEADS*HID
#define C2 32   // D_OUT
#define NEG 0.2f

#define NB 1024   // coarse buckets
#define BSH 7     // bucket = dst >> 7 (128 nodes per bucket)
#define EPB 4096  // edges per binning block

static __device__ __forceinline__ float leaky(float x) { return x > 0.f ? x : NEG * x; }

// ---------------- CSR build: bucket-binned counting sort ----------------

__global__ __launch_bounds__(256) void k_chist(const int* __restrict__ ei, int* __restrict__ bhist) {
    __shared__ int h[NB];
    int t = threadIdx.x;
    for (int i = t; i < NB; i += 256) h[i] = 0;
    __syncthreads();
    int e0 = blockIdx.x * EPB;
#pragma unroll
    for (int j = 0; j < 16; j++) {
        int e = e0 + t + 256 * j;
        if (e < EE) atomicAdd(&h[ei[EE + e] >> BSH], 1);
    }
    __syncthreads();
    for (int i = t; i < NB; i += 256) {
        int c = h[i];
        if (c) atomicAdd(&bhist[i], c);
    }
}

__global__ __launch_bounds__(256) void k_bscan(const int* __restrict__ bhist,
                                               int* __restrict__ gbase, int* __restrict__ gcur) {
    __shared__ int s[256];
    int t = threadIdx.x;
    int base = t * 4;
    int v[4];
    int run = 0;
#pragma unroll
    for (int j = 0; j < 4; j++) {
        v[j] = run;
        run += bhist[base + j];
    }
    int val = run;
    s[t] = val;
    __syncthreads();
    for (int off = 1; off < 256; off <<= 1) {
        int add = (t >= off) ? s[t - off] : 0;
        __syncthreads();
        val += add;
        s[t] = val;
        __syncthreads();
    }
    int texcl = val - run;
#pragma unroll
    for (int j = 0; j < 4; j++) {
        gbase[base + j] = texcl + v[j];
        gcur[base + j] = texcl + v[j];
    }
}

__global__ __launch_bounds__(256) void k_bin(const int* __restrict__ ei, int* __restrict__ gcur,
                                             int2* __restrict__ binned) {
    __shared__ int h[NB];
    __shared__ int base[NB];
    int t = threadIdx.x;
    for (int i = t; i < NB; i += 256) h[i] = 0;
    __syncthreads();
    int e0 = blockIdx.x * EPB;
    int src[16], dst[16];
#pragma unroll
    for (int j = 0; j < 16; j++) {
        int e = e0 + t + 256 * j;
        if (e < EE) {
            src[j] = ei[e];
            dst[j] = ei[EE + e];
            atomicAdd(&h[dst[j] >> BSH], 1);
        } else
            dst[j] = -1;
    }
    __syncthreads();
    for (int i = t; i < NB; i += 256) {
        int c = h[i];
        if (c) base[i] = atomicAdd(&gcur[i], c);
        h[i] = 0;  // reuse as local cursor
    }
    __syncthreads();
#pragma unroll
    for (int j = 0; j < 16; j++) {
        if (dst[j] >= 0) {
            int b = dst[j] >> BSH;
            int r = atomicAdd(&h[b], 1);
            binned[base[b] + r] = make_int2(src[j], dst[j]);
        }
    }
}

// one block per bucket: counting sort of its edges; writes deg, rs, csr
__global__ __launch_bounds__(256) void k_bsort(const int2* __restrict__ binned,
                                               const int* __restrict__ gbase,
                                               const int* __restrict__ bhist,
                                               int* __restrict__ rs, int* __restrict__ deg,
                                               int* __restrict__ csr) {
    __shared__ int h[128], cur[128], sc[128];
    int b = blockIdx.x, t = threadIdx.x;
    if (t < 128) h[t] = 0;
    __syncthreads();
    int gb = gbase[b], cnt = bhist[b];
    for (int i = t; i < cnt; i += 256) atomicAdd(&h[binned[gb + i].y & 127], 1);
    __syncthreads();
    if (t < 128) sc[t] = h[t];
    __syncthreads();
    for (int off = 1; off < 128; off <<= 1) {
        int add = 0;
        if (t < 128 && t >= off) add = sc[t - off];
        __syncthreads();
        if (t < 128) sc[t] += add;
        __syncthreads();
    }
    if (t < 128) {
        int node = b * 128 + t;
        int excl = sc[t] - h[t];
        if (node < NN) {
            rs[node] = gb + excl;
            deg[node] = h[t];
        }
        cur[t] = excl;
    }
    __syncthreads();
    for (int i = t; i < cnt; i += 256) {
        int2 e = binned[gb + i];
        int r = atomicAdd(&cur[e.y & 127], 1);
        csr[gb + r] = e.x;
    }
}

// ---------------- GEMM1: h1 = x @ W1, fused al_src/al_dst ----------------
__global__ __launch_bounds__(256, 2) void k_gemm1(
    const float* __restrict__ x, const float* __restrict__ W1,
    const float* __restrict__ a_s, const float* __restrict__ a_d,
    float* __restrict__ h1, float* __restrict__ als, float* __restrict__ ald) {
    __shared__ float xs[64 * 128];   // 32 KB
    __shared__ float wsh[128 * 64];  // 32 KB
    int t = threadIdx.x;
    int base = blockIdx.x * 64;
    for (int i = t; i < 2048; i += 256) ((float4*)wsh)[i] = ((const float4*)W1)[i];
    int maxn = NN - base;
    if (maxn > 64) maxn = 64;
    for (int i = t; i < 2048; i += 256) {
        int flat = i * 4;
        int n = flat >> 7;
        if (n < maxn) *(float4*)&xs[flat] = *(const float4*)&x[(size_t)(base + n) * 128 + (flat & 127)];
    }
    __syncthreads();
    int w = t >> 6, c = t & 63;
    int nb = w * 16;
    float acc[16];
#pragma unroll
    for (int j = 0; j < 16; j++) acc[j] = 0.f;
    for (int k = 0; k < 128; k += 4) {
        float w0 = wsh[k * 64 + c], w1 = wsh[(k + 1) * 64 + c];
        float w2 = wsh[(k + 2) * 64 + c], w3 = wsh[(k + 3) * 64 + c];
#pragma unroll
        for (int j = 0; j < 16; j++) {
            float4 xv = *(float4*)&xs[(nb + j) * 128 + k];
            acc[j] = fmaf(xv.x, w0, acc[j]);
            acc[j] = fmaf(xv.y, w1, acc[j]);
            acc[j] = fmaf(xv.z, w2, acc[j]);
            acc[j] = fmaf(xv.w, w3, acc[j]);
        }
    }
    float s_a = a_s[c], d_a = a_d[c];
    int hd = c >> 4;
#pragma unroll
    for (int j = 0; j < 16; j++) {
        int n = base + nb + j;
        float v = acc[j];
        float vs = v * s_a, vd = v * d_a;
#pragma unroll
        for (int off = 1; off < 16; off <<= 1) {
            vs += __shfl_xor(vs, off, 64);
            vd += __shfl_xor(vd, off, 64);
        }
        if (n < NN) {
            h1[(size_t)n * 64 + c] = v;
            if ((c & 15) == 0) {
                als[n * 4 + hd] = vs;
                ald[n * 4 + hd] = vd;
            }
        }
    }
}

// ---------------- Edge pass 1 + fused GEMM2 ----------------
// wave per dst node. Phase A: lane = edge (p = exp(logit - logit_self), no
// reductions needed). Phase B: lane = channel, z and acc accumulated together.
__global__ __launch_bounds__(256) void k_edge1(
    const int* __restrict__ csr, const int* __restrict__ rs, const int* __restrict__ deg,
    const float* __restrict__ h1, const float* __restrict__ als, const float* __restrict__ ald,
    const float* __restrict__ b1, const float* __restrict__ W2,
    const float* __restrict__ as2, const float* __restrict__ ad2,
    float* __restrict__ h2, float* __restrict__ als2, float* __restrict__ ald2) {
    __shared__ float wsh[64 * 32];   // 8 KB: W2
    __shared__ float xld[4][64];     // per-wave x2 row
    __shared__ float pp[4][64][4];   // per-wave per-edge p[head]
    __shared__ int ss[4][64];        // per-wave per-edge src
    int t = threadIdx.x;
    for (int i = t; i < 512; i += 256) ((float4*)wsh)[i] = ((const float4*)W2)[i];
    int w = t >> 6, lane = t & 63, hd = lane >> 4;
    int n = blockIdx.x * 4 + w;  // NN % 4 == 0
    float4 ad4 = *(const float4*)&ald[n * 4];
    float4 an4 = *(const float4*)&als[n * 4];
    // self logits per head (wave-uniform shift; cancels in acc/z ratio)
    float ls0 = leaky(an4.x + ad4.x), ls1 = leaky(an4.y + ad4.y);
    float ls2 = leaky(an4.z + ad4.z), ls3 = leaky(an4.w + ad4.w);
    float z = 1.f;                          // self weight exp(0)
    float acc = h1[n * 64 + lane];          // self contribution
    int s0 = rs[n], d = deg[n];
    for (int i0 = 0; i0 < d; i0 += 64) {
        int e = i0 + lane;
        int src = 0;
        float4 a4 = make_float4(-1e30f, -1e30f, -1e30f, -1e30f);
        if (e < d) {
            src = csr[s0 + e];
            a4 = *(const float4*)&als[src * 4];
        }
        float p0 = __expf(leaky(a4.x + ad4.x) - ls0);  // invalid lane -> 0, never read
        float p1 = __expf(leaky(a4.y + ad4.y) - ls1);
        float p2 = __expf(leaky(a4.z + ad4.z) - ls2);
        float p3 = __expf(leaky(a4.w + ad4.w) - ls3);
        ss[w][lane] = src;
        pp[w][lane][0] = p0;
        pp[w][lane][1] = p1;
        pp[w][lane][2] = p2;
        pp[w][lane][3] = p3;
        int cnt = d - i0;
        if (cnt > 64) cnt = 64;
#pragma unroll 4
        for (int i = 0; i < cnt; i++) {
            int sA = ss[w][i];           // broadcast
            float pA = pp[w][i][hd];     // 4 consecutive banks, conflict-free
            z += pA;
            acc = fmaf(pA, h1[sA * 64 + lane], acc);
        }
    }
    float o = acc / (z + 1e-16f) + b1[lane];
    float xv = o > 0.f ? o : expm1f(o);  // ELU

    // ---- fused GEMM2: h2[n] = x2row @ W2 ----
    xld[w][lane] = xv;
    __syncthreads();
    int hi = lane >> 5, cc = lane & 31;
    float accn = 0.f;
#pragma unroll
    for (int k = 0; k < 32; k++) {
        float xk = xld[w][hi * 32 + k];
        accn = fmaf(xk, wsh[(hi * 32 + k) * 32 + cc], accn);
    }
    accn += __shfl_xor(accn, 32, 64);
    float vs = accn * as2[cc], vd = accn * ad2[cc];
#pragma unroll
    for (int off = 1; off < 32; off <<= 1) {
        vs += __shfl_xor(vs, off, 64);
        vd += __shfl_xor(vd, off, 64);
    }
    if (lane < 32) h2[n * 32 + lane] = accn;
    if (lane == 0) {
        als2[n] = vs;
        ald2[n] = vd;
    }
}

// ---------------- Edge pass 2: wave per node, halves split the edge list ----------------
__global__ __launch_bounds__(256) void k_edge2(
    const int* __restrict__ csr, const int* __restrict__ rs, const int* __restrict__ deg,
    const float* __restrict__ h2, const float* __restrict__ als, const float* __restrict__ ald,
    const float* __restrict__ b2, float* __restrict__ out) {
    __shared__ float2 pst[4][64];  // {src, p}
    int t = threadIdx.x;
    int w = t >> 6, lane = t & 63;
    int n = blockIdx.x * 4 + w;  // NN % 4 == 0
    int cc = lane & 31, half = lane >> 5;
    float ad = ald[n];
    float lself = leaky(als[n] + ad);
    float z = half == 0 ? 1.f : 0.f;
    float acc = half == 0 ? h2[n * 32 + cc] : 0.f;
    int s0 = rs[n], d = deg[n];
    for (int i0 = 0; i0 < d; i0 += 64) {
        int e = i0 + lane;
        int src = 0;
        float av = -1e30f;
        if (e < d) {
            src = csr[s0 + e];
            av = als[src];
        }
        float p = __expf(leaky(av + ad) - lself);
        pst[w][lane] = make_float2(__int_as_float(src), p);
        int cnt = d - i0;
        if (cnt > 64) cnt = 64;
#pragma unroll 4
        for (int i = half; i < cnt; i += 2) {  // halves interleave over edges
            float2 q = pst[w][i];
            int sA = __float_as_int(q.x);
            float pA = q.y;
            z += pA;
            acc = fmaf(pA, h2[sA * 32 + cc], acc);
        }
    }
    acc += __shfl_xor(acc, 32, 64);
    z += __shfl_xor(z, 32, 64);
    if (half == 0) out[n * 32 + cc] = acc / (z + 1e-16f) + b2[cc];
}

// ---------------- launcher ----------------
extern "C" void kernel_launch(void* const* d_in, const int* in_sizes, int n_in,
                              void* d_out, int out_size, void* d_ws, size_t ws_size,
                              hipStream_t stream) {
    const float* x = (const float*)d_in[0];
    const int* ei = (const int*)d_in[1];
    const float* W1 = (const float*)d_in[2];
    const float* as1 = (const float*)d_in[3];
    const float* ad1 = (const float*)d_in[4];
    const float* b1 = (const float*)d_in[5];
    const float* W2 = (const float*)d_in[6];
    const float* as2 = (const float*)d_in[7];
    const float* ad2 = (const float*)d_in[8];
    const float* b2 = (const float*)d_in[9];
    float* out = (float*)d_out;

    char* p = (char*)d_ws;
    auto alloc = [&](size_t bytes) -> char* {
        char* r = p;
        p += (bytes + 255) & ~(size_t)255;
        return r;
    };
    int* csr = (int*)alloc((size_t)EE * 4);
    int* rs = (int*)alloc((size_t)NN * 4);
    int* deg = (int*)alloc((size_t)NN * 4);
    int* bhist = (int*)alloc(NB * 4);
    int* gbase = (int*)alloc(NB * 4);
    int* gcur = (int*)alloc(NB * 4);
    float* h1 = (float*)alloc((size_t)NN * C1 * 4);
    float* als1 = (float*)alloc((size_t)NN * 4 * 4);
    float* ald1 = (float*)alloc((size_t)NN * 4 * 4);
    // region X: binned (12.8 MB) aliases h2/als2/ald2; binned is dead before
    // k_edge1 writes h2.
    char* regionX = alloc((size_t)NN * C2 * 4 + (size_t)NN * 4 * 2 + 512);
    int2* binned = (int2*)regionX;
    float* h2 = (float*)regionX;
    float* als2 = (float*)(regionX + (size_t)NN * C2 * 4);
    float* ald2 = (float*)(regionX + (size_t)NN * C2 * 4 + (size_t)NN * 4);
    (void)ws_size;

    hipMemsetAsync(bhist, 0, NB * 4, stream);

    int nbin = (EE + EPB - 1) / EPB;  // 391
    k_chist<<<nbin, 256, 0, stream>>>(ei, bhist);
    k_bscan<<<1, 256, 0, stream>>>(bhist, gbase, gcur);
    k_bin<<<nbin, 256, 0, stream>>>(ei, gcur, binned);
    k_bsort<<<(NN + 127) / 128, 256, 0, stream>>>(binned, gbase, bhist, rs, deg, csr);

    k_gemm1<<<(NN + 63) / 64, 256, 0, stream>>>(x, W1, as1, ad1, h1, als1, ald1);
    k_edge1<<<NN / 4, 256, 0, stream>>>(csr, rs, deg, h1, als1, ald1, b1, W2, as2, ad2,
                                        h2, als2, ald2);
    k_edge2<<<NN / 4, 256, 0, stream>>>(csr, rs, deg, h2, als2, ald2, b2, out);
}